// Round 1
// baseline (231.247 us; speedup 1.0000x reference)
//
#include <hip/hip_runtime.h>
#include <hip/hip_bf16.h>

#define N_NODES   4096
#define E_EDGES   262144
#define IN_DIM    256
#define EDGE_DIM  16
#define NAF       16
#define LATENT    128
#define NBT       5

#define LATENT_OFF 0
#define ATOMS_OFF  (N_NODES * LATENT)                 // 524288
#define BONDS_OFF  (ATOMS_OFF + N_NODES * NAF)        // 589824

// hash table: 2^20 u64 slots = 8 MB, load factor 0.25
#define TBITS 20
#define TSIZE (1u << TBITS)
#define TMASK (TSIZE - 1u)

typedef float    f32x4  __attribute__((ext_vector_type(4)));
typedef float    f32x4v __attribute__((ext_vector_type(4)));
typedef short    bf16x8 __attribute__((ext_vector_type(8)));
typedef unsigned u32x2  __attribute__((ext_vector_type(2)));
typedef unsigned u32x4  __attribute__((ext_vector_type(4)));

// silu via v_rcp_f32 instead of IEEE divide (saves ~7 VALU + keeps 1 trans);
// rel err ~1 ulp f32, negligible vs bf16-split error budget (absmax 9.8e-4).
__device__ __forceinline__ float silu_f(float x) {
    return x * __builtin_amdgcn_rcpf(1.0f + __expf(-x));
}

// HW packed f32->bf16 RNE (gfx950 v_cvt_pk_bf16_f32), bit-trick fallback.
__device__ __forceinline__ unsigned pack_bf16x2(float lo, float hi) {
#if __has_builtin(__builtin_amdgcn_cvt_pk_bf16_f32)
    typedef __bf16 bf16x2_t __attribute__((ext_vector_type(2)));
    union { bf16x2_t v; unsigned u; } c;
    c.v = __builtin_amdgcn_cvt_pk_bf16_f32(lo, hi);
    return c.u;
#else
    union { float f; unsigned u; } a, b;
    a.f = lo; b.f = hi;
    const unsigned ra = (a.u + 0x7FFFu + ((a.u >> 16) & 1u)) >> 16;
    const unsigned rb = (b.u + 0x7FFFu + ((b.u >> 16) & 1u)) >> 16;
    return ra | (rb << 16);
#endif
}

__device__ __forceinline__ float bf_lo(unsigned u) {
    union { unsigned x; float f; } c; c.x = u << 16; return c.f;
}
__device__ __forceinline__ float bf_hi(unsigned u) {
    union { unsigned x; float f; } c; c.x = u & 0xFFFF0000u; return c.f;
}

// split fp32x8 into bf16 hi + bf16 lo fragments (x = hi + lo exactly to 2^-18)
__device__ __forceinline__ void split_bf16(const float4 x0, const float4 x1,
                                           bf16x8* hi, bf16x8* lo) {
    union { bf16x8 v; unsigned u[4]; } H, L;
    H.u[0] = pack_bf16x2(x0.x, x0.y);
    H.u[1] = pack_bf16x2(x0.z, x0.w);
    H.u[2] = pack_bf16x2(x1.x, x1.y);
    H.u[3] = pack_bf16x2(x1.z, x1.w);
    L.u[0] = pack_bf16x2(x0.x - bf_lo(H.u[0]), x0.y - bf_hi(H.u[0]));
    L.u[1] = pack_bf16x2(x0.z - bf_lo(H.u[1]), x0.w - bf_hi(H.u[1]));
    L.u[2] = pack_bf16x2(x1.x - bf_lo(H.u[2]), x1.y - bf_hi(H.u[2]));
    L.u[3] = pack_bf16x2(x1.z - bf_lo(H.u[3]), x1.w - bf_hi(H.u[3]));
    *hi = H.v; *lo = L.v;
}

// async gather: per-lane 16B global -> LDS[uniform base + lane*16]
__device__ __forceinline__ void gld_lds16(const void* g, void* l) {
    __builtin_amdgcn_global_load_lds(
        (const __attribute__((address_space(1))) unsigned*)g,
        (__attribute__((address_space(3))) unsigned*)l, 16, 0, 0);
}

__device__ __forceinline__ int hlookup(const unsigned long long* __restrict__ tab,
                                       unsigned key) {
    unsigned h = (key * 2654435761u) >> (32 - TBITS);
    while (true) {
        const unsigned long long cur = tab[h];
        if (cur == 0ULL) return -1;
        if ((unsigned)(cur >> 18) == key + 1u) return (int)(cur & 0x3FFFFu);
        h = (h + 1u) & TMASK;
    }
}

// ---------------------------------------------------------------------------
// k_hash: blocks 0..1023 : hash insert (winner = max edge id per key)
//         block  1024    : prepack A1pre/A2pre MFMA frag records (R9 form)
// Split out of the GEMM kernel so (a) it gets its own small-VGPR allocation
// (full occupancy for the latency-bound atomics), (b) rocprof shows its
// duration separately.
// ---------------------------------------------------------------------------
__global__ __launch_bounds__(256) void k_hash(const int* __restrict__ eidx,
                                              const float* __restrict__ Wb,
                                              const float* __restrict__ bb,
                                              const float* __restrict__ Wbs,
                                              unsigned long long* __restrict__ tab,
                                              u32x4* __restrict__ A1pre,
                                              u32x4* __restrict__ A2pre) {
    const int blk = blockIdx.x;
    const int c   = threadIdx.x;

    if (blk < 1024) {
        // ---- hash insert
        const int k = blk * 256 + c;
        const unsigned j = (unsigned)eidx[k];
        const unsigned i = (unsigned)eidx[E_EDGES + k];
        const unsigned key = (j << 12) | i;
        const unsigned long long mine =
            ((unsigned long long)(key + 1u) << 18) | (unsigned)k;
        unsigned h = (key * 2654435761u) >> (32 - TBITS);
        while (true) {
            unsigned long long cur = tab[h];
            if (cur == 0ULL) {
                const unsigned long long old = atomicCAS(&tab[h], 0ULL, mine);
                if (old == 0ULL) return;
                cur = old;
            }
            if ((unsigned)(cur >> 18) == key + 1u) {
                atomicMax(&tab[h], mine);
                return;
            }
            h = (h + 1u) & TMASK;
        }
    } else {
        // ---- prepack: A1 = {Wb pair, Wb pair, pk(bb,0), 0}; A2 = {Wbs pair x2, 0, 0}
#pragma unroll
        for (int ee = 0; ee < 4; ++ee) {
            const int idx  = c + 256 * ee;
            const int g    = idx >> 6;
            const int lane = idx & 63;
            const int m    = lane & 15;
            const int q    = lane >> 4;

            const float4 w = *(const float4*)(Wb + (16 * g + m) * EDGE_DIM + 4 * q);
            u32x4 r1;
            r1.x = pack_bf16x2(w.x, w.y);
            r1.y = pack_bf16x2(w.z, w.w);
            r1.z = pack_bf16x2(bb[16 * g + m], 0.0f);
            r1.w = 0u;
            A1pre[idx] = r1;

            u32x4 r2;
            if (m < NBT) {
                const float4 ws = *(const float4*)(Wbs + m * IN_DIM + 16 * g + 4 * q);
                r2.x = pack_bf16x2(ws.x, ws.y);
                r2.y = pack_bf16x2(ws.z, ws.w);
            } else {
                r2.x = 0u; r2.y = 0u;
            }
            r2.z = 0u; r2.w = 0u;
            A2pre[idx] = r2;
        }
    }
}

// ---------------------------------------------------------------------------
// k_gemm1: sact16 = bf16(silu(s@Wsh^T + bsh)), MFMA tiles,
//          split-bf16 (3 MFMA/chunk) for fp32-grade accuracy
// ---------------------------------------------------------------------------
__global__ __launch_bounds__(256) void k_gemm1(const float* __restrict__ s,
                                               const float* __restrict__ Wsh,
                                               const float* __restrict__ bsh,
                                               unsigned short* __restrict__ sact16) {
    const int blk = blockIdx.x;
    const int c   = threadIdx.x;

    // ---- GEMM1 tile: wave -> (row_tile, col_tile); 256 x 16 tiles
    const int lane = c & 63;
    const int wv   = c >> 6;
    const int wave = blk * 4 + wv;
    const int m    = lane & 15;
    const int q    = lane >> 4;
    const int row0 = (wave >> 4) * 16;
    const int col0 = (wave & 15) * 16;

    f32x4v acc;
    {
        const float bias = bsh[col0 + m];
        acc[0] = bias; acc[1] = bias; acc[2] = bias; acc[3] = bias;
    }

    const float* ap = s   + (size_t)(row0 + m) * IN_DIM + 8 * q;
    const float* bp = Wsh + (size_t)(col0 + m) * IN_DIM + 8 * q;

#pragma unroll
    for (int c8 = 0; c8 < 8; ++c8) {
        const float4 a0 = *(const float4*)(ap + 32 * c8);
        const float4 a1 = *(const float4*)(ap + 32 * c8 + 4);
        const float4 b0 = *(const float4*)(bp + 32 * c8);
        const float4 b1 = *(const float4*)(bp + 32 * c8 + 4);
        bf16x8 Ah, Al, Bh, Bl;
        split_bf16(a0, a1, &Ah, &Al);
        split_bf16(b0, b1, &Bh, &Bl);
        acc = __builtin_amdgcn_mfma_f32_16x16x32_bf16(Ah, Bh, acc, 0, 0, 0);
        acc = __builtin_amdgcn_mfma_f32_16x16x32_bf16(Al, Bh, acc, 0, 0, 0);
        acc = __builtin_amdgcn_mfma_f32_16x16x32_bf16(Ah, Bl, acc, 0, 0, 0);
    }

    // D: col = col0+m, rows row0+4q+r -> pure silu, bf16 short stores
#pragma unroll
    for (int r = 0; r < 4; ++r) {
        const int row = row0 + 4 * q + r;
        const float v = silu_f(acc[r]);
        sact16[(size_t)row * IN_DIM + col0 + m] =
            (unsigned short)(pack_bf16x2(v, 0.0f) & 0xFFFFu);
    }
}

// ---------------------------------------------------------------------------
// K4: blocks 0..4095  : MFMA edge kernel (R12 gather staging + R9 bias form)
//     blocks 4096..4671: GEMM2 — atoms/latent = sact16@Wa^T + ba
//                        (A = bf16 sact16 direct; B = Wa split-bf16, 2 MFMA)
// ---------------------------------------------------------------------------
__global__ __launch_bounds__(256, 5) void k_edges_mfma(const int* __restrict__ eidx,
                                                       const float* __restrict__ e,
                                                       const unsigned long long* __restrict__ tab,
                                                       const unsigned short* __restrict__ sact16,
                                                       const u32x4* __restrict__ A1pre,
                                                       const u32x4* __restrict__ A2pre,
                                                       const float* __restrict__ bbs,
                                                       const float* __restrict__ Wa,
                                                       const float* __restrict__ ba,
                                                       float* __restrict__ out) {
    __shared__ unsigned lds_all[4][2048];   // 8 KB/wave (edge blocks only)
    const int blk  = blockIdx.x;
    const int lane = threadIdx.x & 63;
    const int wv   = threadIdx.x >> 6;
    const int m    = lane & 15;
    const int q    = lane >> 4;

    if (blk >= 4096) {
        // ---- GEMM2: wave -> (row_tile, col_tile) over 256 x 9 tiles
        const int wave = (blk - 4096) * 4 + wv;   // 0..2303
        const int rt = wave / 9;
        const int ct = wave - rt * 9;
        const int row0  = rt * 16;
        const int n_abs = ct * 16 + m;            // 0..143

        f32x4v acc;
        {
            const float bias = ba[n_abs];
            acc[0] = bias; acc[1] = bias; acc[2] = bias; acc[3] = bias;
        }

        const unsigned short* apu = sact16 + (size_t)(row0 + m) * IN_DIM + 8 * q;
        const float*          bp  = Wa + (size_t)n_abs * IN_DIM + 8 * q;

#pragma unroll
        for (int c8 = 0; c8 < 8; ++c8) {
            const bf16x8 A = *(const bf16x8*)(apu + 32 * c8);
            const float4 b0 = *(const float4*)(bp + 32 * c8);
            const float4 b1 = *(const float4*)(bp + 32 * c8 + 4);
            bf16x8 Bh, Bl;
            split_bf16(b0, b1, &Bh, &Bl);
            acc = __builtin_amdgcn_mfma_f32_16x16x32_bf16(A, Bh, acc, 0, 0, 0);
            acc = __builtin_amdgcn_mfma_f32_16x16x32_bf16(A, Bl, acc, 0, 0, 0);
        }
#pragma unroll
        for (int r = 0; r < 4; ++r) {
            const int row = row0 + 4 * q + r;
            if (n_abs < NAF)
                out[ATOMS_OFF + (size_t)row * NAF + n_abs] = acc[r];
            else
                out[LATENT_OFF + (size_t)row * LATENT + (n_abs - NAF)] = acc[r];
        }
        return;
    }

    // ---- edge tile
    const int k0 = __builtin_amdgcn_readfirstlane((blk * 4 + wv) * 16);
    unsigned* myl = lds_all[wv];
    const short one_q0 = (q == 0) ? (short)0x3F80 : (short)0;  // bf16(1.0)

    f32x4v acc_init;
#pragma unroll
    for (int r = 0; r < 4; ++r) {
        const int bond = 4 * q + r;
        acc_init[r] = (bond < NBT) ? bbs[bond] : 0.0f;
    }

    const unsigned j_m = (unsigned)eidx[k0 + m];
    const unsigned i_m = (unsigned)eidx[E_EDGES + k0 + m];

    const char* si_base = (const char*)(sact16 + (size_t)i_m * IN_DIM);  // 512 B rows
    const char* sj_base = (const char*)(sact16 + (size_t)j_m * IN_DIM);

    // stage half 0 (channels 0..127) -> LDS (async gather)
#pragma unroll
    for (int u = 0; u < 4; ++u)
        gld_lds16(si_base + (4 * u + q) * 16, (char*)myl + u * 1024);
#pragma unroll
    for (int u = 0; u < 4; ++u)
        gld_lds16(sj_base + (4 * u + q) * 16, (char*)myl + 4096 + u * 1024);

    // T14 async-stage split: issue half-1 gathers into REGISTERS now, so the
    // HBM/L2 latency hides under run_half(0); ds_write them after, and the
    // second vmcnt(0) drain disappears entirely.  (+32 VGPR, 48->~85 < 102.)
    u32x4 st[8];
#pragma unroll
    for (int u = 0; u < 4; ++u)
        st[u]     = *(const u32x4*)(si_base + 256 + (4 * u + q) * 16);
#pragma unroll
    for (int u = 0; u < 4; ++u)
        st[4 + u] = *(const u32x4*)(sj_base + 256 + (4 * u + q) * 16);

    // hash probes + e gather (overlap staging)
    const unsigned wf = (unsigned)hlookup(tab, (j_m << 12) | i_m);
    const int      wr = hlookup(tab, (i_m << 12) | j_m);

    f32x4 es = *(const f32x4*)(e + (size_t)wf * EDGE_DIM + 4 * q);
    if (wr >= 0)
        es += *(const f32x4*)(e + (size_t)wr * EDGE_DIM + 4 * q);
    es *= 0.5f;

    union { bf16x8 v; short s[8]; unsigned u[4]; } B1;
    B1.u[0] = pack_bf16x2(es[0], es[1]);
    B1.u[1] = pack_bf16x2(es[2], es[3]);
    B1.s[4] = one_q0; B1.s[5] = 0;
    B1.u[3] = 0u;

    const u32x4* a1p = A1pre + lane;
    const u32x4* a2p = A2pre + lane;

    f32x4v acc0 = acc_init;
    f32x4v acc1 = {0.0f, 0.0f, 0.0f, 0.0f};

    const int qh = q >> 1;
    const int qw = 2 * (q & 1);
    const int mw = m * 4;

    auto run_half = [&](int h) {
#pragma unroll
        for (int gp = 0; gp < 8; ++gp) {
            const int g     = 8 * h + gp;
            const int chunk = 2 * gp + qh;
            const int offw  = (chunk >> 2) * 256 + (chunk & 3) * 64 + mw + qw;

            const u32x2 wi = *(const u32x2*)(myl + offw);
            const u32x2 wj = *(const u32x2*)(myl + 1024 + offw);

            f32x4v C1;
            C1[0] = bf_lo(wi.x) + bf_lo(wj.x);
            C1[1] = bf_hi(wi.x) + bf_hi(wj.x);
            C1[2] = bf_lo(wi.y) + bf_lo(wj.y);
            C1[3] = bf_hi(wi.y) + bf_hi(wj.y);

            const u32x4 r1 = a1p[g * 64];
            const u32x4 r2 = a2p[g * 64];
            union { bf16x8 v; unsigned u[4]; } A1, A2;
            A1.u[0] = r1.x; A1.u[1] = r1.y; A1.u[2] = r1.z; A1.u[3] = 0u;
            A2.u[0] = r2.x; A2.u[1] = r2.y; A2.u[2] = 0u;   A2.u[3] = 0u;

            const f32x4v P = __builtin_amdgcn_mfma_f32_16x16x32_bf16(A1.v, B1.v, C1, 0, 0, 0);

            union { bf16x8 v; unsigned u[4]; } B2;
            B2.u[0] = pack_bf16x2(silu_f(P[0]), silu_f(P[1]));
            B2.u[1] = pack_bf16x2(silu_f(P[2]), silu_f(P[3]));
            B2.u[2] = 0u; B2.u[3] = 0u;

            if (g & 1) acc1 = __builtin_amdgcn_mfma_f32_16x16x32_bf16(A2.v, B2.v, acc1, 0, 0, 0);
            else       acc0 = __builtin_amdgcn_mfma_f32_16x16x32_bf16(A2.v, B2.v, acc0, 0, 0, 0);
        }
    };

    __asm__ __volatile__("s_waitcnt vmcnt(0)" ::: "memory");
    run_half(0);

    // half-0 LDS reads drained -> safe to overwrite the staging buffer
    __asm__ __volatile__("s_waitcnt lgkmcnt(0)" ::: "memory");
    {
        char* wp = (char*)myl + lane * 16;
#pragma unroll
        for (int u = 0; u < 4; ++u)
            *((u32x4*)(wp + u * 1024)) = st[u];
#pragma unroll
        for (int u = 0; u < 4; ++u)
            *((u32x4*)(wp + 4096 + u * 1024)) = st[4 + u];
    }
    __asm__ __volatile__("s_waitcnt lgkmcnt(0)" ::: "memory");
    run_half(1);

    const f32x4v accT = acc0 + acc1;
    float* op = out + BONDS_OFF + (size_t)(k0 + m) * NBT;
    if (q == 0) {
        __builtin_nontemporal_store(accT[0], op + 0);
        __builtin_nontemporal_store(accT[1], op + 1);
        __builtin_nontemporal_store(accT[2], op + 2);
        __builtin_nontemporal_store(accT[3], op + 3);
    } else if (q == 1) {
        __builtin_nontemporal_store(accT[0], op + 4);
    }
}

// ---------------------------------------------------------------------------
extern "C" void kernel_launch(void* const* d_in, const int* in_sizes, int n_in,
                              void* d_out, int out_size, void* d_ws, size_t ws_size,
                              hipStream_t stream) {
    const float* s   = (const float*)d_in[0];
    const float* e   = (const float*)d_in[1];
    const int*   eix = (const int*)d_in[3];
    const float* Wsh = (const float*)d_in[4];
    const float* bsh = (const float*)d_in[5];
    const float* Wb  = (const float*)d_in[6];
    const float* bbo = (const float*)d_in[7];
    const float* Wbs = (const float*)d_in[8];
    const float* bbs = (const float*)d_in[9];
    const float* Wa  = (const float*)d_in[10];
    const float* ba  = (const float*)d_in[11];
    float* out = (float*)d_out;

    char* ws = (char*)d_ws;
    unsigned short*     sact16 = (unsigned short*)ws;             // 2 MB @ 0
    u32x4*              A1pre  = (u32x4*)(ws + (2u << 20));       // 16 KB
    u32x4*              A2pre  = (u32x4*)(ws + (2u << 20) + 16384);
    unsigned long long* tab    = (unsigned long long*)(ws + (3u << 20)); // 8 MB

    (void)hipMemsetAsync(tab, 0x00, TSIZE * sizeof(unsigned long long), stream);

    k_hash<<<1025, 256, 0, stream>>>(eix, Wb, bbo, Wbs, tab, A1pre, A2pre);
    k_gemm1<<<1024, 256, 0, stream>>>(s, Wsh, bsh, sact16);
    k_edges_mfma<<<4672, 256, 0, stream>>>(eix, e, tab, sact16,
                                           A1pre, A2pre, bbs, Wa, ba, out);
}

// Round 4
// 184.161 us; speedup vs baseline: 1.2557x; 1.2557x over previous
//
#include <hip/hip_runtime.h>
#include <hip/hip_bf16.h>

#define N_NODES   4096
#define E_EDGES   262144
#define IN_DIM    256
#define EDGE_DIM  16
#define NAF       16
#define LATENT    128
#define NBT       5

#define LATENT_OFF 0
#define ATOMS_OFF  (N_NODES * LATENT)                 // 524288
#define BONDS_OFF  (ATOMS_OFF + N_NODES * NAF)        // 589824

// hash table: 2^20 u64 slots = 8 MB, load factor 0.25
#define TBITS 20
#define TSIZE (1u << TBITS)
#define TMASK (TSIZE - 1u)

typedef float    f32x4  __attribute__((ext_vector_type(4)));
typedef float    f32x4v __attribute__((ext_vector_type(4)));
typedef short    bf16x8 __attribute__((ext_vector_type(8)));
typedef unsigned u32x2  __attribute__((ext_vector_type(2)));
typedef unsigned u32x4  __attribute__((ext_vector_type(4)));

// silu via v_rcp_f32 (accuracy validated in R1: absmax unchanged)
__device__ __forceinline__ float silu_f(float x) {
    return x * __builtin_amdgcn_rcpf(1.0f + __expf(-x));
}

__device__ __forceinline__ unsigned pack_bf16x2(float lo, float hi) {
#if __has_builtin(__builtin_amdgcn_cvt_pk_bf16_f32)
    typedef __bf16 bf16x2_t __attribute__((ext_vector_type(2)));
    union { bf16x2_t v; unsigned u; } c;
    c.v = __builtin_amdgcn_cvt_pk_bf16_f32(lo, hi);
    return c.u;
#else
    union { float f; unsigned u; } a, b;
    a.f = lo; b.f = hi;
    const unsigned ra = (a.u + 0x7FFFu + ((a.u >> 16) & 1u)) >> 16;
    const unsigned rb = (b.u + 0x7FFFu + ((b.u >> 16) & 1u)) >> 16;
    return ra | (rb << 16);
#endif
}

__device__ __forceinline__ float bf_lo(unsigned u) {
    union { unsigned x; float f; } c; c.x = u << 16; return c.f;
}
__device__ __forceinline__ float bf_hi(unsigned u) {
    union { unsigned x; float f; } c; c.x = u & 0xFFFF0000u; return c.f;
}

// split fp32x8 into bf16 hi + bf16 lo fragments (x = hi + lo exactly to 2^-18)
__device__ __forceinline__ void split_bf16(const float4 x0, const float4 x1,
                                           bf16x8* hi, bf16x8* lo) {
    union { bf16x8 v; unsigned u[4]; } H, L;
    H.u[0] = pack_bf16x2(x0.x, x0.y);
    H.u[1] = pack_bf16x2(x0.z, x0.w);
    H.u[2] = pack_bf16x2(x1.x, x1.y);
    H.u[3] = pack_bf16x2(x1.z, x1.w);
    L.u[0] = pack_bf16x2(x0.x - bf_lo(H.u[0]), x0.y - bf_hi(H.u[0]));
    L.u[1] = pack_bf16x2(x0.z - bf_lo(H.u[1]), x0.w - bf_hi(H.u[1]));
    L.u[2] = pack_bf16x2(x1.x - bf_lo(H.u[2]), x1.y - bf_hi(H.u[2]));
    L.u[3] = pack_bf16x2(x1.z - bf_lo(H.u[3]), x1.w - bf_hi(H.u[3]));
    *hi = H.v; *lo = L.v;
}

// async gather: per-lane 16B global -> LDS[uniform base + lane*16]
__device__ __forceinline__ void gld_lds16(const void* g, void* l) {
    __builtin_amdgcn_global_load_lds(
        (const __attribute__((address_space(1))) unsigned*)g,
        (__attribute__((address_space(3))) unsigned*)l, 16, 0, 0);
}

__device__ __forceinline__ unsigned hashh(unsigned key) {
    return (key * 2654435761u) >> (32 - TBITS);
}

__device__ __forceinline__ int hlookup(const unsigned long long* __restrict__ tab,
                                       unsigned key) {
    unsigned h = hashh(key);
    while (true) {
        const unsigned long long cur = tab[h];
        if (cur == 0ULL) return -1;
        if ((unsigned)(cur >> 18) == key + 1u) return (int)(cur & 0x3FFFFu);
        h = (h + 1u) & TMASK;
    }
}

// ---------------------------------------------------------------------------
// k_front (R0 structure, PASSED): blocks 0..1023  : GEMM1
//                                 blocks 1024..2047: hash insert
//                                 block  2048      : prepack A1pre/A2pre
// ---------------------------------------------------------------------------
__global__ __launch_bounds__(256) void k_front(const float* __restrict__ s,
                                               const float* __restrict__ Wsh,
                                               const float* __restrict__ bsh,
                                               const int* __restrict__ eidx,
                                               const float* __restrict__ Wb,
                                               const float* __restrict__ bb,
                                               const float* __restrict__ Wbs,
                                               unsigned short* __restrict__ sact16,
                                               unsigned long long* __restrict__ tab,
                                               u32x4* __restrict__ A1pre,
                                               u32x4* __restrict__ A2pre) {
    const int blk = blockIdx.x;
    const int c   = threadIdx.x;

    if (blk >= 1024) {
        if (blk < 2048) {
            // ---- hash insert (winner = max edge id per key)
            const int k = (blk - 1024) * 256 + c;
            const unsigned j = (unsigned)eidx[k];
            const unsigned i = (unsigned)eidx[E_EDGES + k];
            const unsigned key = (j << 12) | i;
            const unsigned long long mine =
                ((unsigned long long)(key + 1u) << 18) | (unsigned)k;
            unsigned h = hashh(key);
            while (true) {
                unsigned long long cur = tab[h];
                if (cur == 0ULL) {
                    const unsigned long long old = atomicCAS(&tab[h], 0ULL, mine);
                    if (old == 0ULL) return;
                    cur = old;
                }
                if ((unsigned)(cur >> 18) == key + 1u) {
                    atomicMax(&tab[h], mine);
                    return;
                }
                h = (h + 1u) & TMASK;
            }
        } else {
            // ---- prepack: A1 = {Wb pair x2, pk(bb,0), 0}; A2 = {Wbs pair x2, 0, 0}
#pragma unroll
            for (int ee = 0; ee < 4; ++ee) {
                const int idx  = c + 256 * ee;
                const int g    = idx >> 6;
                const int lane = idx & 63;
                const int mm   = lane & 15;
                const int qq   = lane >> 4;

                const float4 w = *(const float4*)(Wb + (16 * g + mm) * EDGE_DIM + 4 * qq);
                u32x4 r1;
                r1.x = pack_bf16x2(w.x, w.y);
                r1.y = pack_bf16x2(w.z, w.w);
                r1.z = pack_bf16x2(bb[16 * g + mm], 0.0f);
                r1.w = 0u;
                A1pre[idx] = r1;

                u32x4 r2;
                if (mm < NBT) {
                    const float4 ws = *(const float4*)(Wbs + mm * IN_DIM + 16 * g + 4 * qq);
                    r2.x = pack_bf16x2(ws.x, ws.y);
                    r2.y = pack_bf16x2(ws.z, ws.w);
                } else {
                    r2.x = 0u; r2.y = 0u;
                }
                r2.z = 0u; r2.w = 0u;
                A2pre[idx] = r2;
            }
        }
        return;
    }

    // ---- GEMM1 tile: wave -> (row_tile, col_tile); 256 x 16 tiles
    const int lane = c & 63;
    const int wv   = c >> 6;
    const int wave = blk * 4 + wv;
    const int m    = lane & 15;
    const int q    = lane >> 4;
    const int row0 = (wave >> 4) * 16;
    const int col0 = (wave & 15) * 16;

    f32x4v acc;
    {
        const float bias = bsh[col0 + m];
        acc[0] = bias; acc[1] = bias; acc[2] = bias; acc[3] = bias;
    }

    const float* ap = s   + (size_t)(row0 + m) * IN_DIM + 8 * q;
    const float* bp = Wsh + (size_t)(col0 + m) * IN_DIM + 8 * q;

#pragma unroll
    for (int c8 = 0; c8 < 8; ++c8) {
        const float4 a0 = *(const float4*)(ap + 32 * c8);
        const float4 a1 = *(const float4*)(ap + 32 * c8 + 4);
        const float4 b0 = *(const float4*)(bp + 32 * c8);
        const float4 b1 = *(const float4*)(bp + 32 * c8 + 4);
        bf16x8 Ah, Al, Bh, Bl;
        split_bf16(a0, a1, &Ah, &Al);
        split_bf16(b0, b1, &Bh, &Bl);
        acc = __builtin_amdgcn_mfma_f32_16x16x32_bf16(Ah, Bh, acc, 0, 0, 0);
        acc = __builtin_amdgcn_mfma_f32_16x16x32_bf16(Al, Bh, acc, 0, 0, 0);
        acc = __builtin_amdgcn_mfma_f32_16x16x32_bf16(Ah, Bl, acc, 0, 0, 0);
    }

#pragma unroll
    for (int r = 0; r < 4; ++r) {
        const int row = row0 + 4 * q + r;
        const float v = silu_f(acc[r]);
        sact16[(size_t)row * IN_DIM + col0 + m] =
            (unsigned short)(pack_bf16x2(v, 0.0f) & 0xFFFFu);
    }
}

// fence helpers. Static-count invariant (R3 post-mortem): every VMEM op
// issued between a counted wait and the cluster it waits on must be a
// statically-issued, SB0-pinned op. All data-dependent loads (hash slow
// path) happen BEFORE the first staging cluster -> only ever OLDER than a
// counted wait -> waits become conservative, never loose.
#define SB0()    __builtin_amdgcn_sched_barrier(0)
#define LGKM0()  do { __asm__ __volatile__("s_waitcnt lgkmcnt(0)" ::: "memory"); SB0(); } while (0)
#define VMW(n)   do { __asm__ __volatile__("s_waitcnt vmcnt(" #n ")" ::: "memory"); SB0(); } while (0)

// ---------------------------------------------------------------------------
// k_edges_mfma: blocks 0..4095  : edge tiles (1 tile/wave), quarter-staged
//                                 X/Y double buffer, counted-vmcnt pipeline
//               blocks 4096..4671: GEMM2 — atoms/latent = sact16@Wa^T + ba
// LDS: 8 KB/wave = 2 x 4 KB quarter-buffers -> 32 KB/block, 5 blocks/CU.
// ---------------------------------------------------------------------------
__global__ __launch_bounds__(256, 5) void k_edges_mfma(const int* __restrict__ eidx,
                                                       const float* __restrict__ e,
                                                       const unsigned long long* __restrict__ tab,
                                                       const unsigned short* __restrict__ sact16,
                                                       const u32x4* __restrict__ A1pre,
                                                       const u32x4* __restrict__ A2pre,
                                                       const float* __restrict__ bbs,
                                                       const float* __restrict__ Wa,
                                                       const float* __restrict__ ba,
                                                       float* __restrict__ out) {
    __shared__ unsigned lds_all[4][2048];   // 8 KB/wave
    const int blk  = blockIdx.x;
    const int lane = threadIdx.x & 63;
    const int wv   = threadIdx.x >> 6;
    const int m    = lane & 15;
    const int q    = lane >> 4;

    if (blk >= 4096) {
        // ---- GEMM2: wave -> (row_tile, col_tile) over 256 x 9 tiles
        const int wave = (blk - 4096) * 4 + wv;   // 0..2303
        const int rt = wave / 9;
        const int ct = wave - rt * 9;
        const int row0  = rt * 16;
        const int n_abs = ct * 16 + m;            // 0..143

        f32x4v acc;
        {
            const float bias = ba[n_abs];
            acc[0] = bias; acc[1] = bias; acc[2] = bias; acc[3] = bias;
        }

        const unsigned short* apu = sact16 + (size_t)(row0 + m) * IN_DIM + 8 * q;
        const float*          bp  = Wa + (size_t)n_abs * IN_DIM + 8 * q;

#pragma unroll
        for (int c8 = 0; c8 < 8; ++c8) {
            const bf16x8 A = *(const bf16x8*)(apu + 32 * c8);
            const float4 b0 = *(const float4*)(bp + 32 * c8);
            const float4 b1 = *(const float4*)(bp + 32 * c8 + 4);
            bf16x8 Bh, Bl;
            split_bf16(b0, b1, &Bh, &Bl);
            acc = __builtin_amdgcn_mfma_f32_16x16x32_bf16(A, Bh, acc, 0, 0, 0);
            acc = __builtin_amdgcn_mfma_f32_16x16x32_bf16(A, Bl, acc, 0, 0, 0);
        }
#pragma unroll
        for (int r = 0; r < 4; ++r) {
            const int row = row0 + 4 * q + r;
            if (n_abs < NAF)
                out[ATOMS_OFF + (size_t)row * NAF + n_abs] = acc[r];
            else
                out[LATENT_OFF + (size_t)row * LATENT + (n_abs - NAF)] = acc[r];
        }
        return;
    }

    // ---- edge tile: 1 tile (16 edges) per wave, as R0
    const int k0 = __builtin_amdgcn_readfirstlane((blk * 4 + wv) * 16);
    unsigned* myl = lds_all[wv];
    const short one_q0 = (q == 0) ? (short)0x3F80 : (short)0;  // bf16(1.0)

    f32x4v acc_init;
#pragma unroll
    for (int r = 0; r < 4; ++r) {
        const int bond = 4 * q + r;
        acc_init[r] = (bond < NBT) ? bbs[bond] : 0.0f;
    }
    const u32x4* a1p = A1pre + lane;
    const u32x4* a2p = A2pre + lane;
    const int qh = q >> 1;
    const int qw = 2 * (q & 1);
    const int mw = m * 4;

    // -------- region A: all data-dependent VMEM (indices, hash, e) --------
    const unsigned j_m = (unsigned)eidx[k0 + m];
    const unsigned i_m = (unsigned)eidx[E_EDGES + k0 + m];

    const char* si_base = (const char*)(sact16 + (size_t)i_m * IN_DIM);  // 512 B rows
    const char* sj_base = (const char*)(sact16 + (size_t)j_m * IN_DIM);

    const int wf = hlookup(tab, (j_m << 12) | i_m);     // always hits
    const int wr = hlookup(tab, (i_m << 12) | j_m);     // may miss

    // reverse-e load made UNCONDITIONAL (static issue count); mask the value.
    const float rsc = (wr >= 0) ? 0.5f : 0.0f;
    const int   wrc = (wr >= 0) ? wr : 0;
    const f32x4 ef = *(const f32x4*)(e + (size_t)wf  * EDGE_DIM + 4 * q);
    const f32x4 er = *(const f32x4*)(e + (size_t)wrc * EDGE_DIM + 4 * q);

    // -------- staging clusters (SB0-pinned, 4 ops each) --------
    // quarter p = 16B-chunks 8p..8p+7 of each 512B row (si + sj)
    auto stage_q = [&](int p, int qb) {
        gld_lds16(si_base + p * 128 + (q)     * 16, (char*)myl + qb);
        gld_lds16(si_base + p * 128 + (4 + q) * 16, (char*)myl + qb + 1024);
        gld_lds16(sj_base + p * 128 + (q)     * 16, (char*)myl + qb + 2048);
        gld_lds16(sj_base + p * 128 + (4 + q) * 16, (char*)myl + qb + 3072);
        SB0();
    };

    stage_q(0, 0);        // Q0 -> X   [4 ops]
    stage_q(1, 4096);     // Q1 -> Y   [4 ops]

    // B1 build (compiler inserts its own waits for ef/er — older than Q0/Q1,
    // so at worst it over-drains; never loosens the counted waits below)
    union { bf16x8 v; short s[8]; unsigned u[4]; } B1;
    {
        const f32x4 es = ef * 0.5f + er * rsc;
        B1.u[0] = pack_bf16x2(es[0], es[1]);
        B1.u[1] = pack_bf16x2(es[2], es[3]);
        B1.s[4] = one_q0; B1.s[5] = 0;
        B1.u[3] = 0u;
    }

    f32x4v acc0 = acc_init;
    f32x4v acc1 = {0.0f, 0.0f, 0.0f, 0.0f};

    // quarter compute: groups g = gbase..gbase+3, buffer at u32 offset qb4
    auto qcompute = [&](int qb4, int gbase) {
#pragma unroll
        for (int gp = 0; gp < 4; ++gp) {
            const int g   = gbase + gp;
            const int cl  = 2 * gp + qh;                                  // 0..7
            const int off = (cl >> 2) * 256 + (cl & 3) * 64 + mw + qw;    // u32 units

            const u32x2 wi = *(const u32x2*)(myl + qb4 + off);
            const u32x2 wj = *(const u32x2*)(myl + qb4 + 512 + off);

            f32x4v C1;
            C1[0] = bf_lo(wi.x) + bf_lo(wj.x);
            C1[1] = bf_hi(wi.x) + bf_hi(wj.x);
            C1[2] = bf_lo(wi.y) + bf_lo(wj.y);
            C1[3] = bf_hi(wi.y) + bf_hi(wj.y);

            const u32x4 r1 = a1p[g * 64];
            const u32x4 r2 = a2p[g * 64];
            union { bf16x8 v; unsigned u[4]; } A1, A2;
            A1.u[0] = r1.x; A1.u[1] = r1.y; A1.u[2] = r1.z; A1.u[3] = 0u;
            A2.u[0] = r2.x; A2.u[1] = r2.y; A2.u[2] = 0u;   A2.u[3] = 0u;

            const f32x4v P = __builtin_amdgcn_mfma_f32_16x16x32_bf16(A1.v, B1.v, C1, 0, 0, 0);

            union { bf16x8 v; unsigned u[4]; } B2;
            B2.u[0] = pack_bf16x2(silu_f(P[0]), silu_f(P[1]));
            B2.u[1] = pack_bf16x2(silu_f(P[2]), silu_f(P[3]));
            B2.u[2] = 0u; B2.u[3] = 0u;

            if (gp & 1) acc1 = __builtin_amdgcn_mfma_f32_16x16x32_bf16(A2.v, B2.v, acc1, 0, 0, 0);
            else        acc0 = __builtin_amdgcn_mfma_f32_16x16x32_bf16(A2.v, B2.v, acc0, 0, 0, 0);
        }
    };

    // -------- counted-vmcnt quarter pipeline --------
    VMW(4);               // Q0 done (newest 4 = Q1 cluster)
    qcompute(0, 0);       // compute Q0 @ X
    LGKM0();              // X's ds_reads retired before overwrite
    stage_q(2, 0);        // Q2 -> X

    VMW(4);               // Q1 done (newest 4 = Q2 cluster)
    qcompute(1024, 4);    // compute Q1 @ Y
    LGKM0();
    stage_q(3, 4096);     // Q3 -> Y

    VMW(4);               // Q2 done (newest 4 = Q3 cluster)
    qcompute(0, 8);       // compute Q2 @ X

    VMW(0);               // Q3 done
    qcompute(1024, 12);   // compute Q3 @ Y

    // -------- store bonds --------
    const f32x4v accT = acc0 + acc1;
    float* op = out + BONDS_OFF + (size_t)(k0 + m) * NBT;
    if (q == 0) {
        __builtin_nontemporal_store(accT[0], op + 0);
        __builtin_nontemporal_store(accT[1], op + 1);
        __builtin_nontemporal_store(accT[2], op + 2);
        __builtin_nontemporal_store(accT[3], op + 3);
    } else if (q == 1) {
        __builtin_nontemporal_store(accT[0], op + 4);
    }
}

// ---------------------------------------------------------------------------
extern "C" void kernel_launch(void* const* d_in, const int* in_sizes, int n_in,
                              void* d_out, int out_size, void* d_ws, size_t ws_size,
                              hipStream_t stream) {
    const float* s   = (const float*)d_in[0];
    const float* e   = (const float*)d_in[1];
    const int*   eix = (const int*)d_in[3];
    const float* Wsh = (const float*)d_in[4];
    const float* bsh = (const float*)d_in[5];
    const float* Wb  = (const float*)d_in[6];
    const float* bbo = (const float*)d_in[7];
    const float* Wbs = (const float*)d_in[8];
    const float* bbs = (const float*)d_in[9];
    const float* Wa  = (const float*)d_in[10];
    const float* ba  = (const float*)d_in[11];
    float* out = (float*)d_out;

    char* ws = (char*)d_ws;
    unsigned short*     sact16 = (unsigned short*)ws;             // 2 MB @ 0
    u32x4*              A1pre  = (u32x4*)(ws + (2u << 20));       // 16 KB
    u32x4*              A2pre  = (u32x4*)(ws + (2u << 20) + 16384);
    unsigned long long* tab    = (unsigned long long*)(ws + (3u << 20)); // 8 MB

    (void)hipMemsetAsync(tab, 0x00, TSIZE * sizeof(unsigned long long), stream);

    k_front<<<2049, 256, 0, stream>>>(s, Wsh, bsh, eix, Wb, bbo, Wbs,
                                      sact16, tab, A1pre, A2pre);
    k_edges_mfma<<<4672, 256, 0, stream>>>(eix, e, tab, sact16,
                                           A1pre, A2pre, bbs, Wa, ba, out);
}

// Round 5
// 181.944 us; speedup vs baseline: 1.2710x; 1.0122x over previous
//
#include <hip/hip_runtime.h>
#include <hip/hip_bf16.h>

#define N_NODES   4096
#define E_EDGES   262144
#define IN_DIM    256
#define EDGE_DIM  16
#define NAF       16
#define LATENT    128
#define NBT       5

#define LATENT_OFF 0
#define ATOMS_OFF  (N_NODES * LATENT)                 // 524288
#define BONDS_OFF  (ATOMS_OFF + N_NODES * NAF)        // 589824

// hash table: 2^20 u64 slots = 8 MB, load factor 0.25
#define TBITS 20
#define TSIZE (1u << TBITS)
#define TMASK (TSIZE - 1u)

typedef float    f32x4  __attribute__((ext_vector_type(4)));
typedef float    f32x4v __attribute__((ext_vector_type(4)));
typedef short    bf16x8 __attribute__((ext_vector_type(8)));
typedef unsigned u32x2  __attribute__((ext_vector_type(2)));
typedef unsigned u32x4  __attribute__((ext_vector_type(4)));

// silu via v_rcp_f32 (accuracy validated in R1: absmax unchanged)
__device__ __forceinline__ float silu_f(float x) {
    return x * __builtin_amdgcn_rcpf(1.0f + __expf(-x));
}

__device__ __forceinline__ unsigned pack_bf16x2(float lo, float hi) {
#if __has_builtin(__builtin_amdgcn_cvt_pk_bf16_f32)
    typedef __bf16 bf16x2_t __attribute__((ext_vector_type(2)));
    union { bf16x2_t v; unsigned u; } c;
    c.v = __builtin_amdgcn_cvt_pk_bf16_f32(lo, hi);
    return c.u;
#else
    union { float f; unsigned u; } a, b;
    a.f = lo; b.f = hi;
    const unsigned ra = (a.u + 0x7FFFu + ((a.u >> 16) & 1u)) >> 16;
    const unsigned rb = (b.u + 0x7FFFu + ((b.u >> 16) & 1u)) >> 16;
    return ra | (rb << 16);
#endif
}

__device__ __forceinline__ float bf_lo(unsigned u) {
    union { unsigned x; float f; } c; c.x = u << 16; return c.f;
}
__device__ __forceinline__ float bf_hi(unsigned u) {
    union { unsigned x; float f; } c; c.x = u & 0xFFFF0000u; return c.f;
}

// split fp32x8 into bf16 hi + bf16 lo fragments (x = hi + lo exactly to 2^-18)
__device__ __forceinline__ void split_bf16(const float4 x0, const float4 x1,
                                           bf16x8* hi, bf16x8* lo) {
    union { bf16x8 v; unsigned u[4]; } H, L;
    H.u[0] = pack_bf16x2(x0.x, x0.y);
    H.u[1] = pack_bf16x2(x0.z, x0.w);
    H.u[2] = pack_bf16x2(x1.x, x1.y);
    H.u[3] = pack_bf16x2(x1.z, x1.w);
    L.u[0] = pack_bf16x2(x0.x - bf_lo(H.u[0]), x0.y - bf_hi(H.u[0]));
    L.u[1] = pack_bf16x2(x0.z - bf_lo(H.u[1]), x0.w - bf_hi(H.u[1]));
    L.u[2] = pack_bf16x2(x1.x - bf_lo(H.u[2]), x1.y - bf_hi(H.u[2]));
    L.u[3] = pack_bf16x2(x1.z - bf_lo(H.u[3]), x1.w - bf_hi(H.u[3]));
    *hi = H.v; *lo = L.v;
}

// async gather: per-lane 16B global -> LDS[uniform base + lane*16]
__device__ __forceinline__ void gld_lds16(const void* g, void* l) {
    __builtin_amdgcn_global_load_lds(
        (const __attribute__((address_space(1))) unsigned*)g,
        (__attribute__((address_space(3))) unsigned*)l, 16, 0, 0);
}

__device__ __forceinline__ unsigned hashh(unsigned key) {
    return (key * 2654435761u) >> (32 - TBITS);
}

// 2-slot speculative resolve: s0/s1 = preloaded tab[h], tab[h+1]; slow loop
// only if both miss (rare at load factor 0.25). Slow-path loads are issued
// BEFORE the e-gathers in program order -> only ever make counted waits
// more conservative (R3/R4 invariant).
__device__ __forceinline__ int resolve2(const unsigned long long* __restrict__ tab,
                                        unsigned key, unsigned long long s0,
                                        unsigned long long s1, unsigned h) {
    if ((unsigned)(s0 >> 18) == key + 1u) return (int)(s0 & 0x3FFFFu);
    if (s0 == 0ULL) return -1;
    if ((unsigned)(s1 >> 18) == key + 1u) return (int)(s1 & 0x3FFFFu);
    if (s1 == 0ULL) return -1;
    h = (h + 2u) & TMASK;
    while (true) {
        const unsigned long long cur = tab[h];
        if (cur == 0ULL) return -1;
        if ((unsigned)(cur >> 18) == key + 1u) return (int)(cur & 0x3FFFFu);
        h = (h + 1u) & TMASK;
    }
}

// ---------------------------------------------------------------------------
// k_front (R0 structure, PASSED): blocks 0..1023  : GEMM1
//                                 blocks 1024..2047: hash insert
//                                 block  2048      : prepack A1pre/A2pre
// ---------------------------------------------------------------------------
__global__ __launch_bounds__(256) void k_front(const float* __restrict__ s,
                                               const float* __restrict__ Wsh,
                                               const float* __restrict__ bsh,
                                               const int* __restrict__ eidx,
                                               const float* __restrict__ Wb,
                                               const float* __restrict__ bb,
                                               const float* __restrict__ Wbs,
                                               unsigned short* __restrict__ sact16,
                                               unsigned long long* __restrict__ tab,
                                               u32x4* __restrict__ A1pre,
                                               u32x4* __restrict__ A2pre) {
    const int blk = blockIdx.x;
    const int c   = threadIdx.x;

    if (blk >= 1024) {
        if (blk < 2048) {
            // ---- hash insert (winner = max edge id per key)
            const int k = (blk - 1024) * 256 + c;
            const unsigned j = (unsigned)eidx[k];
            const unsigned i = (unsigned)eidx[E_EDGES + k];
            const unsigned key = (j << 12) | i;
            const unsigned long long mine =
                ((unsigned long long)(key + 1u) << 18) | (unsigned)k;
            unsigned h = hashh(key);
            while (true) {
                unsigned long long cur = tab[h];
                if (cur == 0ULL) {
                    const unsigned long long old = atomicCAS(&tab[h], 0ULL, mine);
                    if (old == 0ULL) return;
                    cur = old;
                }
                if ((unsigned)(cur >> 18) == key + 1u) {
                    atomicMax(&tab[h], mine);
                    return;
                }
                h = (h + 1u) & TMASK;
            }
        } else {
            // ---- prepack: A1 = {Wb pair x2, pk(bb,0), 0}; A2 = {Wbs pair x2, 0, 0}
#pragma unroll
            for (int ee = 0; ee < 4; ++ee) {
                const int idx  = c + 256 * ee;
                const int g    = idx >> 6;
                const int lane = idx & 63;
                const int mm   = lane & 15;
                const int qq   = lane >> 4;

                const float4 w = *(const float4*)(Wb + (16 * g + mm) * EDGE_DIM + 4 * qq);
                u32x4 r1;
                r1.x = pack_bf16x2(w.x, w.y);
                r1.y = pack_bf16x2(w.z, w.w);
                r1.z = pack_bf16x2(bb[16 * g + mm], 0.0f);
                r1.w = 0u;
                A1pre[idx] = r1;

                u32x4 r2;
                if (mm < NBT) {
                    const float4 ws = *(const float4*)(Wbs + mm * IN_DIM + 16 * g + 4 * qq);
                    r2.x = pack_bf16x2(ws.x, ws.y);
                    r2.y = pack_bf16x2(ws.z, ws.w);
                } else {
                    r2.x = 0u; r2.y = 0u;
                }
                r2.z = 0u; r2.w = 0u;
                A2pre[idx] = r2;
            }
        }
        return;
    }

    // ---- GEMM1 tile: wave -> (row_tile, col_tile); 256 x 16 tiles
    const int lane = c & 63;
    const int wv   = c >> 6;
    const int wave = blk * 4 + wv;
    const int m    = lane & 15;
    const int q    = lane >> 4;
    const int row0 = (wave >> 4) * 16;
    const int col0 = (wave & 15) * 16;

    f32x4v acc;
    {
        const float bias = bsh[col0 + m];
        acc[0] = bias; acc[1] = bias; acc[2] = bias; acc[3] = bias;
    }

    const float* ap = s   + (size_t)(row0 + m) * IN_DIM + 8 * q;
    const float* bp = Wsh + (size_t)(col0 + m) * IN_DIM + 8 * q;

#pragma unroll
    for (int c8 = 0; c8 < 8; ++c8) {
        const float4 a0 = *(const float4*)(ap + 32 * c8);
        const float4 a1 = *(const float4*)(ap + 32 * c8 + 4);
        const float4 b0 = *(const float4*)(bp + 32 * c8);
        const float4 b1 = *(const float4*)(bp + 32 * c8 + 4);
        bf16x8 Ah, Al, Bh, Bl;
        split_bf16(a0, a1, &Ah, &Al);
        split_bf16(b0, b1, &Bh, &Bl);
        acc = __builtin_amdgcn_mfma_f32_16x16x32_bf16(Ah, Bh, acc, 0, 0, 0);
        acc = __builtin_amdgcn_mfma_f32_16x16x32_bf16(Al, Bh, acc, 0, 0, 0);
        acc = __builtin_amdgcn_mfma_f32_16x16x32_bf16(Ah, Bl, acc, 0, 0, 0);
    }

#pragma unroll
    for (int r = 0; r < 4; ++r) {
        const int row = row0 + 4 * q + r;
        const float v = silu_f(acc[r]);
        sact16[(size_t)row * IN_DIM + col0 + m] =
            (unsigned short)(pack_bf16x2(v, 0.0f) & 0xFFFFu);
    }
}

// fence helpers. Static-count invariant (R3/R4): hand-counted waits may only
// be made MORE conservative by dynamic VMEM ops; all data-dependent loads
// (hash slow path) are issued BEFORE the e-gathers, whose compiler wait is
// the effective full drain point. After that point every VMEM op is a
// statically-issued, SB0-pinned cluster.
#define SB0()    __builtin_amdgcn_sched_barrier(0)
#define LGKM0()  do { __asm__ __volatile__("s_waitcnt lgkmcnt(0)" ::: "memory"); SB0(); } while (0)
#define VMW(n)   do { __asm__ __volatile__("s_waitcnt vmcnt(" #n ")" ::: "memory"); SB0(); } while (0)

// ---------------------------------------------------------------------------
// k_edges_mfma: blocks 0..4095  : edge tiles (1 tile/wave), quarter-staged
//                                 X/Y double buffer; staging issue OVERLAPS
//                                 the hash/e dependency chain (R5 reorder)
//               blocks 4096..4671: GEMM2 — atoms/latent = sact16@Wa^T + ba
// LDS: 8 KB/wave = 2 x 4 KB quarter-buffers -> 32 KB/block, 5 blocks/CU.
// ---------------------------------------------------------------------------
__global__ __launch_bounds__(256, 5) void k_edges_mfma(const int* __restrict__ eidx,
                                                       const float* __restrict__ e,
                                                       const unsigned long long* __restrict__ tab,
                                                       const unsigned short* __restrict__ sact16,
                                                       const u32x4* __restrict__ A1pre,
                                                       const u32x4* __restrict__ A2pre,
                                                       const float* __restrict__ bbs,
                                                       const float* __restrict__ Wa,
                                                       const float* __restrict__ ba,
                                                       float* __restrict__ out) {
    __shared__ unsigned lds_all[4][2048];   // 8 KB/wave
    const int blk  = blockIdx.x;
    const int lane = threadIdx.x & 63;
    const int wv   = threadIdx.x >> 6;
    const int m    = lane & 15;
    const int q    = lane >> 4;

    if (blk >= 4096) {
        // ---- GEMM2: wave -> (row_tile, col_tile) over 256 x 9 tiles
        const int wave = (blk - 4096) * 4 + wv;   // 0..2303
        const int rt = wave / 9;
        const int ct = wave - rt * 9;
        const int row0  = rt * 16;
        const int n_abs = ct * 16 + m;            // 0..143

        f32x4v acc;
        {
            const float bias = ba[n_abs];
            acc[0] = bias; acc[1] = bias; acc[2] = bias; acc[3] = bias;
        }

        const unsigned short* apu = sact16 + (size_t)(row0 + m) * IN_DIM + 8 * q;
        const float*          bp  = Wa + (size_t)n_abs * IN_DIM + 8 * q;

#pragma unroll
        for (int c8 = 0; c8 < 8; ++c8) {
            const bf16x8 A = *(const bf16x8*)(apu + 32 * c8);
            const float4 b0 = *(const float4*)(bp + 32 * c8);
            const float4 b1 = *(const float4*)(bp + 32 * c8 + 4);
            bf16x8 Bh, Bl;
            split_bf16(b0, b1, &Bh, &Bl);
            acc = __builtin_amdgcn_mfma_f32_16x16x32_bf16(A, Bh, acc, 0, 0, 0);
            acc = __builtin_amdgcn_mfma_f32_16x16x32_bf16(A, Bl, acc, 0, 0, 0);
        }
#pragma unroll
        for (int r = 0; r < 4; ++r) {
            const int row = row0 + 4 * q + r;
            if (n_abs < NAF)
                out[ATOMS_OFF + (size_t)row * NAF + n_abs] = acc[r];
            else
                out[LATENT_OFF + (size_t)row * LATENT + (n_abs - NAF)] = acc[r];
        }
        return;
    }

    // ---- edge tile: 1 tile (16 edges) per wave
    const int k0 = __builtin_amdgcn_readfirstlane((blk * 4 + wv) * 16);
    unsigned* myl = lds_all[wv];
    const short one_q0 = (q == 0) ? (short)0x3F80 : (short)0;  // bf16(1.0)

    f32x4v acc_init;
#pragma unroll
    for (int r = 0; r < 4; ++r) {
        const int bond = 4 * q + r;
        acc_init[r] = (bond < NBT) ? bbs[bond] : 0.0f;
    }
    const u32x4* a1p = A1pre + lane;
    const u32x4* a2p = A2pre + lane;
    const int qh = q >> 1;
    const int qw = 2 * (q & 1);
    const int mw = m * 4;

    // -------- issue phase: everything that can fly in parallel --------
    const unsigned j_m = (unsigned)eidx[k0 + m];
    const unsigned i_m = (unsigned)eidx[E_EDGES + k0 + m];

    const char* si_base = (const char*)(sact16 + (size_t)i_m * IN_DIM);  // 512 B rows
    const char* sj_base = (const char*)(sact16 + (size_t)j_m * IN_DIM);

    const unsigned keyF = (j_m << 12) | i_m, keyR = (i_m << 12) | j_m;
    const unsigned hF = hashh(keyF), hR = hashh(keyR);
    // speculative 2-slot probes (fly in parallel with staging)
    const unsigned long long sF0 = tab[hF];
    const unsigned long long sF1 = tab[(hF + 1u) & TMASK];
    const unsigned long long sR0 = tab[hR];
    const unsigned long long sR1 = tab[(hR + 1u) & TMASK];

    // staging clusters (SB0-pinned, 4 ops each); quarter p = 16B-chunks
    // 8p..8p+7 of each 512B row (si + sj)
    auto stage_q = [&](int p, int qb) {
        gld_lds16(si_base + p * 128 + (q)     * 16, (char*)myl + qb);
        gld_lds16(si_base + p * 128 + (4 + q) * 16, (char*)myl + qb + 1024);
        gld_lds16(sj_base + p * 128 + (q)     * 16, (char*)myl + qb + 2048);
        gld_lds16(sj_base + p * 128 + (4 + q) * 16, (char*)myl + qb + 3072);
        SB0();
    };

    stage_q(0, 0);        // Q0 -> X   (overlaps the hash/e chain below)
    stage_q(1, 4096);     // Q1 -> Y

    // -------- resolve phase (overlapped with staging flight) --------
    const int wf = resolve2(tab, keyF, sF0, sF1, hF);
    const int wr = resolve2(tab, keyR, sR0, sR1, hR);

    // reverse-e load UNCONDITIONAL (static issue count); mask the value.
    const float rsc = (wr >= 0) ? 0.5f : 0.0f;
    const int   wrc = (wr >= 0) ? wr : 0;
    const f32x4 ef = *(const f32x4*)(e + (size_t)wf  * EDGE_DIM + 4 * q);
    const f32x4 er = *(const f32x4*)(e + (size_t)wrc * EDGE_DIM + 4 * q);

    union { bf16x8 v; short s[8]; unsigned u[4]; } B1;
    {
        const f32x4 es = ef * 0.5f + er * rsc;
        B1.u[0] = pack_bf16x2(es[0], es[1]);
        B1.u[1] = pack_bf16x2(es[2], es[3]);
        B1.s[4] = one_q0; B1.s[5] = 0;
        B1.u[3] = 0u;
    }

    f32x4v acc0 = acc_init;
    f32x4v acc1 = {0.0f, 0.0f, 0.0f, 0.0f};

    // quarter compute: groups g = gbase..gbase+3, buffer at u32 offset qb4
    auto qcompute = [&](int qb4, int gbase) {
#pragma unroll
        for (int gp = 0; gp < 4; ++gp) {
            const int g   = gbase + gp;
            const int cl  = 2 * gp + qh;                                  // 0..7
            const int off = (cl >> 2) * 256 + (cl & 3) * 64 + mw + qw;    // u32 units

            const u32x2 wi = *(const u32x2*)(myl + qb4 + off);
            const u32x2 wj = *(const u32x2*)(myl + qb4 + 512 + off);

            f32x4v C1;
            C1[0] = bf_lo(wi.x) + bf_lo(wj.x);
            C1[1] = bf_hi(wi.x) + bf_hi(wj.x);
            C1[2] = bf_lo(wi.y) + bf_lo(wj.y);
            C1[3] = bf_hi(wi.y) + bf_hi(wj.y);

            const u32x4 r1 = a1p[g * 64];
            const u32x4 r2 = a2p[g * 64];
            union { bf16x8 v; unsigned u[4]; } A1, A2;
            A1.u[0] = r1.x; A1.u[1] = r1.y; A1.u[2] = r1.z; A1.u[3] = 0u;
            A2.u[0] = r2.x; A2.u[1] = r2.y; A2.u[2] = 0u;   A2.u[3] = 0u;

            const f32x4v P = __builtin_amdgcn_mfma_f32_16x16x32_bf16(A1.v, B1.v, C1, 0, 0, 0);

            union { bf16x8 v; unsigned u[4]; } B2;
            B2.u[0] = pack_bf16x2(silu_f(P[0]), silu_f(P[1]));
            B2.u[1] = pack_bf16x2(silu_f(P[2]), silu_f(P[3]));
            B2.u[2] = 0u; B2.u[3] = 0u;

            if (gp & 1) acc1 = __builtin_amdgcn_mfma_f32_16x16x32_bf16(A2.v, B2.v, acc1, 0, 0, 0);
            else        acc0 = __builtin_amdgcn_mfma_f32_16x16x32_bf16(A2.v, B2.v, acc0, 0, 0, 0);
        }
    };

    // -------- counted-vmcnt quarter pipeline --------
    // The compiler's wait for ef/er (youngest loads) already implies Q0+Q1
    // retired (in-order vmcnt); this VMW(0) is the explicit async-LDS fence
    // (rule 21) and is timing-free: the 3-RT hash/e chain >> 1-RT staging.
    VMW(0);
    qcompute(0, 0);       // compute Q0 @ X
    LGKM0();              // X's ds_reads retired before overwrite
    stage_q(2, 0);        // Q2 -> X

    qcompute(1024, 4);    // compute Q1 @ Y (covered by the VMW(0) above)
    LGKM0();
    stage_q(3, 4096);     // Q3 -> Y

    VMW(4);               // Q2 done (outstanding <= {Q2,Q3}; Q3=4 may fly)
    qcompute(0, 8);       // compute Q2 @ X

    VMW(0);               // Q3 done
    qcompute(1024, 12);   // compute Q3 @ Y

    // -------- store bonds --------
    const f32x4v accT = acc0 + acc1;
    float* op = out + BONDS_OFF + (size_t)(k0 + m) * NBT;
    if (q == 0) {
        __builtin_nontemporal_store(accT[0], op + 0);
        __builtin_nontemporal_store(accT[1], op + 1);
        __builtin_nontemporal_store(accT[2], op + 2);
        __builtin_nontemporal_store(accT[3], op + 3);
    } else if (q == 1) {
        __builtin_nontemporal_store(accT[0], op + 4);
    }
}

// ---------------------------------------------------------------------------
extern "C" void kernel_launch(void* const* d_in, const int* in_sizes, int n_in,
                              void* d_out, int out_size, void* d_ws, size_t ws_size,
                              hipStream_t stream) {
    const float* s   = (const float*)d_in[0];
    const float* e   = (const float*)d_in[1];
    const int*   eix = (const int*)d_in[3];
    const float* Wsh = (const float*)d_in[4];
    const float* bsh = (const float*)d_in[5];
    const float* Wb  = (const float*)d_in[6];
    const float* bbo = (const float*)d_in[7];
    const float* Wbs = (const float*)d_in[8];
    const float* bbs = (const float*)d_in[9];
    const float* Wa  = (const float*)d_in[10];
    const float* ba  = (const float*)d_in[11];
    float* out = (float*)d_out;

    char* ws = (char*)d_ws;
    unsigned short*     sact16 = (unsigned short*)ws;             // 2 MB @ 0
    u32x4*              A1pre  = (u32x4*)(ws + (2u << 20));       // 16 KB
    u32x4*              A2pre  = (u32x4*)(ws + (2u << 20) + 16384);
    unsigned long long* tab    = (unsigned long long*)(ws + (3u << 20)); // 8 MB

    (void)hipMemsetAsync(tab, 0x00, TSIZE * sizeof(unsigned long long), stream);

    k_front<<<2049, 256, 0, stream>>>(s, Wsh, bsh, eix, Wb, bbo, Wbs,
                                      sact16, tab, A1pre, A2pre);
    k_edges_mfma<<<4672, 256, 0, stream>>>(eix, e, tab, sact16,
                                           A1pre, A2pre, bbs, Wa, ba, out);
}